// Round 1
// baseline (551.886 us; speedup 1.0000x reference)
//
#include <hip/hip_runtime.h>
#include <hip/hip_fp16.h>

#define CH   16
#define HID  32
#define HIN  254
#define WIN  254
#define HO   128
#define WO   128
#define NB   64
#define SLEN (HO * WO)          // 16384
#define CHUNK 16
#define WARM  32
#define NCHUNK (SLEN / CHUNK)   // 1024

__device__ __forceinline__ float fast_tanh(float x) {
    float ax = __builtin_fabsf(x);
    // tanh(|x|) = (1 - 2^(-2*log2(e)*|x|)) / (1 + 2^(-2*log2(e)*|x|))
    float e = exp2f(ax * -2.8853900817779268f);
    float r = (1.0f - e) * __builtin_amdgcn_rcpf(1.0f + e);
    return __builtin_copysignf(r, x);
}

// ---------------- K1: pad + L2 pool + input projection -------------------
__global__ __launch_bounds__(128) void k_pool(const float* __restrict__ x,
                                              const float* __restrict__ Wih,
                                              const float* __restrict__ bih,
                                              const float* __restrict__ bhh,
                                              float* __restrict__ pooled,
                                              __half* __restrict__ xproj) {
    const int xc = threadIdx.x;   // 0..127 output col
    const int y  = blockIdx.x;    // 0..127 output row
    const int n  = blockIdx.y;    // 0..63  batch

    int r[3], cc[3];
#pragma unroll
    for (int k = 0; k < 3; ++k) {
        r[k]  = min(max(2 * y  - 2 + k, 0), HIN - 1);
        cc[k] = min(max(2 * xc - 2 + k, 0), WIN - 1);
    }

    const float* xn = x + (size_t)n * CH * HIN * WIN;
    float p[CH];
#pragma unroll
    for (int c = 0; c < CH; ++c) {
        const float* b = xn + (size_t)c * HIN * WIN;
        float s = 0.f;
#pragma unroll
        for (int ky = 0; ky < 3; ++ky) {
            const float* rp = b + r[ky] * WIN;
#pragma unroll
            for (int kx = 0; kx < 3; ++kx) {
                float v = rp[cc[kx]];
                s = fmaf(v, v, s);
            }
        }
        float pv = sqrtf(s);
        p[c] = pv;
        pooled[(((size_t)n * CH + c) * HO + y) * WO + xc] = pv;
    }

    // xproj[h] = b_ih[h] + b_hh[h] + sum_c p[c] * Wih[h][c]   (uniform W -> s_loads)
    float acc[HID];
#pragma unroll
    for (int h = 0; h < HID; ++h) acc[h] = bih[h] + bhh[h];
#pragma unroll
    for (int c = 0; c < CH; ++c) {
        float pc = p[c];
#pragma unroll
        for (int h = 0; h < HID; ++h) acc[h] = fmaf(pc, Wih[h * CH + c], acc[h]);
    }

    __half2 hh[HID / 2];
#pragma unroll
    for (int w = 0; w < HID / 2; ++w) hh[w] = __floats2half2_rn(acc[2 * w], acc[2 * w + 1]);

    __half2* dst = (__half2*)(xproj + ((size_t)n * SLEN + (size_t)y * WO + xc) * HID);
#pragma unroll
    for (int w = 0; w < HID / 2; ++w) dst[w] = hh[w];
}

// ---------------- K2: chunked Elman RNN (lane = batch) -------------------
__global__ __launch_bounds__(64) void k_rnn(const __half* __restrict__ xproj,
                                            const float* __restrict__ Whh,
                                            __half* __restrict__ rnn) {
    const int n   = threadIdx.x;   // 0..63 : batch index
    const int cid = blockIdx.x;    // 0..NCHUNK-1
    const int start  = cid * CHUNK;
    const int warm   = min(WARM, start);
    const int t0     = start - warm;
    const int nsteps = warm + CHUNK;

    const __half2* __restrict__ xp2 = (const __half2*)(xproj + (size_t)n * SLEN * HID);
    __half* __restrict__ rn = rnn + (size_t)n * SLEN * HID;

    float h[HID];
#pragma unroll
    for (int i = 0; i < HID; ++i) h[i] = 0.f;

    __half2 cur[16], nxt[16];
#pragma unroll
    for (int w = 0; w < 16; ++w) cur[w] = xp2[(size_t)t0 * 16 + w];

    for (int st = 0; st < nsteps; ++st) {
        const int t  = t0 + st;
        const int tn = (t + 1 < SLEN) ? (t + 1) : t;   // clamped prefetch
#pragma unroll
        for (int w = 0; w < 16; ++w) nxt[w] = xp2[(size_t)tn * 16 + w];

        float xp[HID];
#pragma unroll
        for (int w = 0; w < 16; ++w) {
            float2 f = __half22float2(cur[w]);
            xp[2 * w] = f.x;
            xp[2 * w + 1] = f.y;
        }

        float hn[HID];
#pragma unroll
        for (int i = 0; i < HID; ++i) {     // full unroll: keep arrays in VGPRs
            const float* wr = Whh + i * HID;  // wave-uniform -> scalar loads
            float a0 = xp[i], a1 = 0.f;
#pragma unroll
            for (int j = 0; j < 16; ++j) {
                a0 = fmaf(wr[j],      h[j],      a0);
                a1 = fmaf(wr[j + 16], h[j + 16], a1);
            }
            hn[i] = fast_tanh(a0 + a1);
        }
#pragma unroll
        for (int i = 0; i < HID; ++i) h[i] = hn[i];

        if (t >= start) {
            __half2 o[16];
#pragma unroll
            for (int w = 0; w < 16; ++w) o[w] = __floats2half2_rn(h[2 * w], h[2 * w + 1]);
            __half2* dst = (__half2*)(rn + (size_t)t * HID);
#pragma unroll
            for (int w = 0; w < 16; ++w) dst[w] = o[w];
        }
#pragma unroll
        for (int w = 0; w < 16; ++w) cur[w] = nxt[w];
    }
}

// ---------------- K3: output projection + residual -----------------------
__global__ __launch_bounds__(128) void k_proj(const __half* __restrict__ rnn,
                                              const float* __restrict__ Wfc,
                                              const float* __restrict__ bfc,
                                              const float* __restrict__ pooled,
                                              float* __restrict__ out) {
    const int xc = threadIdx.x;
    const int y  = blockIdx.x;
    const int n  = blockIdx.y;
    const int s  = y * WO + xc;

    const __half2* hr = (const __half2*)(rnn + ((size_t)n * SLEN + s) * HID);
    float hv[HID];
#pragma unroll
    for (int w = 0; w < 16; ++w) {
        float2 f = __half22float2(hr[w]);
        hv[2 * w] = f.x;
        hv[2 * w + 1] = f.y;
    }

#pragma unroll
    for (int c = 0; c < CH; ++c) {
        float a = bfc[c];
#pragma unroll
        for (int j = 0; j < HID; ++j) a = fmaf(hv[j], Wfc[c * HID + j], a);
        size_t idx = (((size_t)n * CH + c) * HO + y) * WO + xc;
        out[idx] = a + pooled[idx];
    }
}

__global__ void k_sentinel(float* o) { o[threadIdx.x] = -12345.0f; }

extern "C" void kernel_launch(void* const* d_in, const int* in_sizes, int n_in,
                              void* d_out, int out_size, void* d_ws, size_t ws_size,
                              hipStream_t stream) {
    const float* x   = (const float*)d_in[0];
    const float* Wih = (const float*)d_in[1];
    const float* Whh = (const float*)d_in[2];
    const float* bih = (const float*)d_in[3];
    const float* bhh = (const float*)d_in[4];
    const float* Wfc = (const float*)d_in[5];
    const float* bfc = (const float*)d_in[6];
    float* out = (float*)d_out;

    const size_t pooledB = (size_t)NB * CH * HO * WO * sizeof(float);   // 64 MiB
    const size_t xpB     = (size_t)NB * SLEN * HID * sizeof(__half);    // 64 MiB
    const size_t rnB     = xpB;                                         // 64 MiB
    if (ws_size < pooledB + xpB + rnB) {
        k_sentinel<<<1, 64, 0, stream>>>(out);
        return;
    }
    float*  pooled = (float*)d_ws;
    __half* xproj  = (__half*)((char*)d_ws + pooledB);
    __half* rnnb   = (__half*)((char*)d_ws + pooledB + xpB);

    k_pool<<<dim3(HO, NB), 128, 0, stream>>>(x, Wih, bih, bhh, pooled, xproj);
    k_rnn <<<dim3(NCHUNK), 64, 0, stream>>>(xproj, Whh, rnnb);
    k_proj<<<dim3(HO, NB), 128, 0, stream>>>(rnnb, Wfc, bfc, pooled, out);
}

// Round 2
// 253.223 us; speedup vs baseline: 2.1794x; 2.1794x over previous
//
#include <hip/hip_runtime.h>
#include <hip/hip_fp16.h>

#define CH   16
#define HID  32
#define HIN  254
#define WIN  254
#define HO   128
#define WO   128
#define NB   64
#define SLEN (HO * WO)          // 16384
#define CHUNK 16
#define WARM  16
#define NCHUNK (SLEN / CHUNK)   // 1024

typedef _Float16 v8h __attribute__((ext_vector_type(8)));
typedef float    v4f __attribute__((ext_vector_type(4)));
typedef unsigned int v4u __attribute__((ext_vector_type(4)));

__device__ __forceinline__ float fast_tanh(float x) {
    float ax = __builtin_fabsf(x);
    float e = exp2f(ax * -2.8853900817779268f);
    float r = (1.0f - e) * __builtin_amdgcn_rcpf(1.0f + e);
    return __builtin_copysignf(r, x);
}

// ---------------- K1: pad + L2 pool + input projection -------------------
__global__ __launch_bounds__(128) void k_pool(const float* __restrict__ x,
                                              const float* __restrict__ Wih,
                                              const float* __restrict__ bih,
                                              const float* __restrict__ bhh,
                                              float* __restrict__ pooled,
                                              __half* __restrict__ xproj) {
    const int xc = threadIdx.x;   // 0..127 output col
    const int y  = blockIdx.x;    // 0..127 output row
    const int n  = blockIdx.y;    // 0..63  batch

    int r[3], cc[3];
#pragma unroll
    for (int k = 0; k < 3; ++k) {
        r[k]  = min(max(2 * y  - 2 + k, 0), HIN - 1);
        cc[k] = min(max(2 * xc - 2 + k, 0), WIN - 1);
    }

    const float* xn = x + (size_t)n * CH * HIN * WIN;
    float p[CH];
#pragma unroll
    for (int c = 0; c < CH; ++c) {
        const float* b = xn + (size_t)c * HIN * WIN;
        float s = 0.f;
#pragma unroll
        for (int ky = 0; ky < 3; ++ky) {
            const float* rp = b + r[ky] * WIN;
#pragma unroll
            for (int kx = 0; kx < 3; ++kx) {
                float v = rp[cc[kx]];
                s = fmaf(v, v, s);
            }
        }
        float pv = sqrtf(s);
        p[c] = pv;
        pooled[(((size_t)n * CH + c) * HO + y) * WO + xc] = pv;
    }

    float acc[HID];
#pragma unroll
    for (int h = 0; h < HID; ++h) acc[h] = bih[h] + bhh[h];
#pragma unroll
    for (int c = 0; c < CH; ++c) {
        float pc = p[c];
#pragma unroll
        for (int h = 0; h < HID; ++h) acc[h] = fmaf(pc, Wih[h * CH + c], acc[h]);
    }

    __half2 hh[HID / 2];
#pragma unroll
    for (int w = 0; w < HID / 2; ++w) hh[w] = __floats2half2_rn(acc[2 * w], acc[2 * w + 1]);

    __half2* dst = (__half2*)(xproj + ((size_t)n * SLEN + (size_t)y * WO + xc) * HID);
#pragma unroll
    for (int w = 0; w < HID / 2; ++w) dst[w] = hh[w];
}

// ---------------- K2: MFMA Elman RNN (1 wave = all 64 batches) -----------
// Layouts (v_mfma_f32_16x16x32_f16, lane l, g=l>>4, q=l&15):
//   A[m][k]: m = q, k = 8*g + e      (half8, 4 VGPRs)
//   B[k][n]: n = q, k = 8*g + e      -> load rows of Whh[n][k] directly
//   D[m][n]: n = q, m = 4*g + r      (float4)   [measured m89 mapping]
// h state kept as A-frags; D->A transpose + xproj ingest + rnn emit all via
// one padded LDS tile [64][40] f16.
__global__ __launch_bounds__(64) void k_rnn(const __half* __restrict__ xproj,
                                            const float* __restrict__ Whh,
                                            __half* __restrict__ rnn) {
    const int l = threadIdx.x;
    const int g = l >> 4;
    const int q = l & 15;
    const int cid = blockIdx.x;
    const int start  = cid * CHUNK;
    const int warm   = min(WARM, start);
    const int t0     = start - warm;
    const int nsteps = warm + CHUNK;     // 16 or 32, always even

    __shared__ __half hbuf[64][40];      // pad 32->40 (80B rows, 16B aligned)

    // constant B fragments: B[k][n] = Whh[n][k] -> lane reads Whh row q (+16*nt)
    v8h bfrag[2];
#pragma unroll
    for (int nt = 0; nt < 2; ++nt) {
        const float* wr = Whh + (size_t)(nt * 16 + q) * HID + 8 * g;
#pragma unroll
        for (int e = 0; e < 8; ++e) bfrag[nt][e] = (_Float16)wr[e];
    }

    // h = 0 in A-frag form
    v8h afrag[4];
#pragma unroll
    for (int mt = 0; mt < 4; ++mt)
#pragma unroll
        for (int e = 0; e < 8; ++e) afrag[mt][e] = (_Float16)0.f;

    // lane l owns batch row l of xproj/rnn in (n, s, h) f16 layout
    const v4u* __restrict__ xpl = (const v4u*)(xproj + (size_t)l * SLEN * HID);
    v4u* __restrict__ rnl = (v4u*)(rnn + (size_t)l * SLEN * HID);

    v4u curA[4], curB[4];
#pragma unroll
    for (int i = 0; i < 4; ++i) curA[i] = xpl[(size_t)t0 * 4 + i];
#pragma unroll
    for (int i = 0; i < 4; ++i) curB[i] = xpl[(size_t)(t0 + 1) * 4 + i];

#define RNN_STEP(CUR, TT)                                                      \
    {                                                                          \
        const int t = (TT);                                                    \
        /* stage xp(t) into LDS rows: lane l -> row l */                       \
        _Pragma("unroll")                                                      \
        for (int i = 0; i < 4; ++i) *(v4u*)&hbuf[l][8 * i] = CUR[i];           \
        /* prefetch xp(t+2) into same regs (ds_write consumed them at issue) */\
        {                                                                      \
            int tn = t + 2; if (tn >= SLEN) tn = SLEN - 1;                     \
            _Pragma("unroll")                                                  \
            for (int i = 0; i < 4; ++i) CUR[i] = xpl[(size_t)tn * 4 + i];      \
        }                                                                      \
        /* read xp C-fragments */                                              \
        v4f acc[4][2];                                                         \
        _Pragma("unroll")                                                      \
        for (int mt = 0; mt < 4; ++mt)                                         \
            _Pragma("unroll")                                                  \
            for (int nt = 0; nt < 2; ++nt)                                     \
                _Pragma("unroll")                                              \
                for (int r = 0; r < 4; ++r)                                    \
                    acc[mt][nt][r] =                                           \
                        __half2float(hbuf[mt * 16 + 4 * g + r][nt * 16 + q]);  \
        /* h_pre = xp + h @ Whh^T : one MFMA per tile (K=32 exact) */          \
        _Pragma("unroll")                                                      \
        for (int mt = 0; mt < 4; ++mt)                                         \
            _Pragma("unroll")                                                  \
            for (int nt = 0; nt < 2; ++nt)                                     \
                acc[mt][nt] = __builtin_amdgcn_mfma_f32_16x16x32_f16(          \
                    afrag[mt], bfrag[nt], acc[mt][nt], 0, 0, 0);               \
        /* tanh, write h back to LDS [b][n] */                                 \
        _Pragma("unroll")                                                      \
        for (int mt = 0; mt < 4; ++mt)                                         \
            _Pragma("unroll")                                                  \
            for (int nt = 0; nt < 2; ++nt)                                     \
                _Pragma("unroll")                                              \
                for (int r = 0; r < 4; ++r) {                                  \
                    float hv = fast_tanh(acc[mt][nt][r]);                      \
                    hbuf[mt * 16 + 4 * g + r][nt * 16 + q] = __float2half(hv); \
                }                                                              \
        /* rebuild A-frags for next step: contiguous 8 f16 of row (b) */       \
        _Pragma("unroll")                                                      \
        for (int mt = 0; mt < 4; ++mt)                                         \
            afrag[mt] = *(const v8h*)&hbuf[mt * 16 + q][8 * g];                \
        /* emit h(t) in (n,s,h) layout: lane l stores its row */               \
        if (t >= start) {                                                      \
            _Pragma("unroll")                                                  \
            for (int i = 0; i < 4; ++i)                                        \
                rnl[(size_t)t * 4 + i] = *(const v4u*)&hbuf[l][8 * i];         \
        }                                                                      \
    }

    for (int st = 0; st < nsteps; st += 2) {
        RNN_STEP(curA, t0 + st)
        RNN_STEP(curB, t0 + st + 1)
    }
#undef RNN_STEP
}

// ---------------- K3: output projection + residual -----------------------
__global__ __launch_bounds__(128) void k_proj(const __half* __restrict__ rnn,
                                              const float* __restrict__ Wfc,
                                              const float* __restrict__ bfc,
                                              const float* __restrict__ pooled,
                                              float* __restrict__ out) {
    const int xc = threadIdx.x;
    const int y  = blockIdx.x;
    const int n  = blockIdx.y;
    const int s  = y * WO + xc;

    const __half2* hr = (const __half2*)(rnn + ((size_t)n * SLEN + s) * HID);
    float hv[HID];
#pragma unroll
    for (int w = 0; w < 16; ++w) {
        float2 f = __half22float2(hr[w]);
        hv[2 * w] = f.x;
        hv[2 * w + 1] = f.y;
    }

#pragma unroll
    for (int c = 0; c < CH; ++c) {
        float a = bfc[c];
#pragma unroll
        for (int j = 0; j < HID; ++j) a = fmaf(hv[j], Wfc[c * HID + j], a);
        size_t idx = (((size_t)n * CH + c) * HO + y) * WO + xc;
        out[idx] = a + pooled[idx];
    }
}

__global__ void k_sentinel(float* o) { o[threadIdx.x] = -12345.0f; }

extern "C" void kernel_launch(void* const* d_in, const int* in_sizes, int n_in,
                              void* d_out, int out_size, void* d_ws, size_t ws_size,
                              hipStream_t stream) {
    const float* x   = (const float*)d_in[0];
    const float* Wih = (const float*)d_in[1];
    const float* Whh = (const float*)d_in[2];
    const float* bih = (const float*)d_in[3];
    const float* bhh = (const float*)d_in[4];
    const float* Wfc = (const float*)d_in[5];
    const float* bfc = (const float*)d_in[6];
    float* out = (float*)d_out;

    const size_t pooledB = (size_t)NB * CH * HO * WO * sizeof(float);   // 64 MiB
    const size_t xpB     = (size_t)NB * SLEN * HID * sizeof(__half);    // 64 MiB
    const size_t rnB     = xpB;                                         // 64 MiB
    if (ws_size < pooledB + xpB + rnB) {
        k_sentinel<<<1, 64, 0, stream>>>(out);
        return;
    }
    float*  pooled = (float*)d_ws;
    __half* xproj  = (__half*)((char*)d_ws + pooledB);
    __half* rnnb   = (__half*)((char*)d_ws + pooledB + xpB);

    k_pool<<<dim3(HO, NB), 128, 0, stream>>>(x, Wih, bih, bhh, pooled, xproj);
    k_rnn <<<dim3(NCHUNK), 64, 0, stream>>>(xproj, Whh, rnnb);
    k_proj<<<dim3(HO, NB), 128, 0, stream>>>(rnnb, Wfc, bfc, pooled, out);
}